// Round 7
// baseline (320.154 us; speedup 1.0000x reference)
//
#include <hip/hip_runtime.h>
#include <hip/hip_fp16.h>

#define THREADS 256

typedef int int4v __attribute__((ext_vector_type(4)));

// ws layout:
//   ws[0] (double)  = sum over edges of (1-p_u)(1-p_v) for u!=v
//   ws[1] (double)  = sum over nodes of probs
//   byte offset 256 = fp16 table q[i] = 1 - probs[i], N_NODES+1 entries
//                     (entry N_NODES is a 0.0 sentinel for self-loop edges)

__device__ __forceinline__ float h2f_bits(unsigned v) {
    __half_raw hr;
    hr.x = (unsigned short)v;
    return __half2float((__half)hr);
}

__device__ __forceinline__ void block_reduce_atomic(float local, double* dst,
                                                    double* sdata) {
    double d = (double)local;
    #pragma unroll
    for (int off = 32; off > 0; off >>= 1)
        d += __shfl_down(d, off, 64);
    int lane = threadIdx.x & 63;
    int wid  = threadIdx.x >> 6;
    if (lane == 0) sdata[wid] = d;
    __syncthreads();
    if (threadIdx.x == 0) {
        double s = 0.0;
        #pragma unroll
        for (int i = 0; i < (THREADS / 64); ++i) s += sdata[i];
        atomicAdd(dst, s);
    }
}

// Build q = 1 - p as fp16 table (+ zero sentinel); fused: reduce sum(probs).
__global__ void __launch_bounds__(THREADS) build_table_kernel(
        const float* __restrict__ probs,
        unsigned short* __restrict__ qt,
        double* __restrict__ ws,
        long long n_nodes) {
    __shared__ double sdata[THREADS / 64];
    long long n4 = n_nodes >> 2;
    const float4* p4 = (const float4*)probs;
    ushort4* q4 = (ushort4*)qt;
    long long tid = (long long)blockIdx.x * blockDim.x + threadIdx.x;
    long long stride = (long long)gridDim.x * blockDim.x;

    if (tid == 0) qt[n_nodes] = (unsigned short)0;  // sentinel: fp16 +0.0

    float local = 0.0f;
    for (long long i = tid; i < n4; i += stride) {
        float4 v = p4[i];
        local += (v.x + v.y) + (v.z + v.w);
        ushort4 q;
        q.x = __half_as_ushort(__float2half(1.0f - v.x));
        q.y = __half_as_ushort(__float2half(1.0f - v.y));
        q.z = __half_as_ushort(__float2half(1.0f - v.z));
        q.w = __half_as_ushort(__float2half(1.0f - v.w));
        q4[i] = q;
    }
    for (long long i = (n4 << 2) + tid; i < n_nodes; i += stride) {
        float p = probs[i];
        local += p;
        qt[i] = __half_as_ushort(__float2half(1.0f - p));
    }

    block_reduce_atomic(local, ws + 1, sdata);
}

// 16 edges (32 gathers) per thread, exact cover. Three phases separated by
// sched_barrier(0) fences so the machine scheduler CANNOT sink gathers down
// to their uses: (A) load all index vectors, (B) issue all 32 gathers,
// (C) consume. Scheduling precedes regalloc -> 32 dests stay live.
__global__ void edge_sum_kernel(
        const unsigned short* __restrict__ qt,
        const int* __restrict__ row,
        const int* __restrict__ col,
        double* __restrict__ ws,
        long long n_edges,
        int sentinel) {
    __shared__ double sdata[THREADS / 64];
    long long n4 = n_edges >> 2;   // int4 groups
    long long G4 = n4 >> 2;        // 4 groups per thread
    long long t  = (long long)blockIdx.x * blockDim.x + threadIdx.x;

    const int4v* row4 = (const int4v*)row;
    const int4v* col4 = (const int4v*)col;

    float local = 0.0f;
    if (t < G4) {
        // ---- phase A: index loads (8x dwordx4, independent) ----
        int4v u[4], v[4];
        #pragma unroll
        for (int k = 0; k < 4; ++k) {
            u[k] = __builtin_nontemporal_load(&row4[t + (long long)k * G4]);
            v[k] = __builtin_nontemporal_load(&col4[t + (long long)k * G4]);
        }
        __builtin_amdgcn_sched_barrier(0);

        // ---- phase B: issue all 32 gathers (self-loops -> zero sentinel) ----
        unsigned av[16], bv[16];
        #pragma unroll
        for (int k = 0; k < 4; ++k) {
            int v0 = (u[k].x == v[k].x) ? sentinel : v[k].x;
            int v1 = (u[k].y == v[k].y) ? sentinel : v[k].y;
            int v2 = (u[k].z == v[k].z) ? sentinel : v[k].z;
            int v3 = (u[k].w == v[k].w) ? sentinel : v[k].w;
            av[4 * k + 0] = qt[u[k].x];
            av[4 * k + 1] = qt[u[k].y];
            av[4 * k + 2] = qt[u[k].z];
            av[4 * k + 3] = qt[u[k].w];
            bv[4 * k + 0] = qt[v0];
            bv[4 * k + 1] = qt[v1];
            bv[4 * k + 2] = qt[v2];
            bv[4 * k + 3] = qt[v3];
        }
        __builtin_amdgcn_sched_barrier(0);

        // ---- phase C: consume ----
        #pragma unroll
        for (int i = 0; i < 16; ++i)
            local += h2f_bits(av[i]) * h2f_bits(bv[i]);
    }

    // tail: edges past 16*G4 (empty when n_edges % 16 == 0)
    long long covered = G4 << 4;
    long long total_threads = (long long)gridDim.x * blockDim.x;
    for (long long e = covered + t; e < n_edges; e += total_threads) {
        int uu = row[e], vv = col[e];
        int vr = (uu == vv) ? sentinel : vv;
        local += h2f_bits(qt[uu]) * h2f_bits(qt[vr]);
    }

    block_reduce_atomic(local, ws, sdata);
}

__global__ void finalize_kernel(const double* __restrict__ ws,
                                const int* __restrict__ batch,
                                long long n_nodes,
                                const float* __restrict__ pc,
                                float* __restrict__ out) {
    double edge_s = ws[0];
    double prob_s = ws[1];
    double G = (double)(batch[n_nodes - 1] + 1);  // batch is sorted
    double ed = edge_s / G;
    double ew = prob_s / G;
    double loss = (double)pc[0] * ed + ew;
    out[0] = (float)loss;
    out[1] = (float)ew;
    out[2] = (float)ed;
}

extern "C" void kernel_launch(void* const* d_in, const int* in_sizes, int n_in,
                              void* d_out, int out_size, void* d_ws, size_t ws_size,
                              hipStream_t stream) {
    const float* probs = (const float*)d_in[0];
    const int* edge_index = (const int*)d_in[1];   // harness passes integers as int32
    const int* batch = (const int*)d_in[2];
    const float* pc = (const float*)d_in[3];

    long long n_nodes = (long long)in_sizes[0];
    long long n_edges = (long long)in_sizes[1] / 2;
    const int* row = edge_index;
    const int* col = edge_index + n_edges;

    double* ws = (double*)d_ws;
    hipMemsetAsync(ws, 0, 2 * sizeof(double), stream);

    unsigned short* qt = (unsigned short*)((char*)d_ws + 256);
    build_table_kernel<<<512, THREADS, 0, stream>>>(probs, qt, ws, n_nodes);

    long long T = (n_edges >> 2) >> 2;           // 16 edges per thread
    long long blocks = (T + THREADS - 1) / THREADS;
    if (blocks < 1) blocks = 1;
    edge_sum_kernel<<<(int)blocks, THREADS, 0, stream>>>(qt, row, col, ws,
                                                         n_edges, (int)n_nodes);

    finalize_kernel<<<1, 1, 0, stream>>>(ws, batch, n_nodes, pc, (float*)d_out);
}

// Round 8
// 311.016 us; speedup vs baseline: 1.0294x; 1.0294x over previous
//
#include <hip/hip_runtime.h>
#include <hip/hip_fp16.h>

#define THREADS 256

typedef int int4v __attribute__((ext_vector_type(4)));

// ws layout:
//   ws[0] (double)  = sum over edges of (1-p_u)(1-p_v) for u!=v
//   ws[1] (double)  = sum over nodes of probs
//   byte offset 256 = fp16 table q[i] = 1 - probs[i], N_NODES+1 entries
//                     (entry N_NODES is a 0.0 sentinel for self-loop edges)

__device__ __forceinline__ float h2f_bits(unsigned v) {
    __half_raw hr;
    hr.x = (unsigned short)v;
    return __half2float((__half)hr);
}

__device__ __forceinline__ void block_reduce_atomic(float local, double* dst,
                                                    double* sdata) {
    double d = (double)local;
    #pragma unroll
    for (int off = 32; off > 0; off >>= 1)
        d += __shfl_down(d, off, 64);
    int lane = threadIdx.x & 63;
    int wid  = threadIdx.x >> 6;
    if (lane == 0) sdata[wid] = d;
    __syncthreads();
    if (threadIdx.x == 0) {
        double s = 0.0;
        #pragma unroll
        for (int i = 0; i < (THREADS / 64); ++i) s += sdata[i];
        atomicAdd(dst, s);
    }
}

// Build q = 1 - p as fp16 table (+ zero sentinel); fused: reduce sum(probs).
__global__ void __launch_bounds__(THREADS) build_table_kernel(
        const float* __restrict__ probs,
        unsigned short* __restrict__ qt,
        double* __restrict__ ws,
        long long n_nodes) {
    __shared__ double sdata[THREADS / 64];
    long long n4 = n_nodes >> 2;
    const float4* p4 = (const float4*)probs;
    ushort4* q4 = (ushort4*)qt;
    long long tid = (long long)blockIdx.x * blockDim.x + threadIdx.x;
    long long stride = (long long)gridDim.x * blockDim.x;

    if (tid == 0) qt[n_nodes] = (unsigned short)0;  // sentinel: fp16 +0.0

    float local = 0.0f;
    for (long long i = tid; i < n4; i += stride) {
        float4 v = p4[i];
        local += (v.x + v.y) + (v.z + v.w);
        ushort4 q;
        q.x = __half_as_ushort(__float2half(1.0f - v.x));
        q.y = __half_as_ushort(__float2half(1.0f - v.y));
        q.z = __half_as_ushort(__float2half(1.0f - v.z));
        q.w = __half_as_ushort(__float2half(1.0f - v.w));
        q4[i] = q;
    }
    for (long long i = (n4 << 2) + tid; i < n_nodes; i += stride) {
        float p = probs[i];
        local += p;
        qt[i] = __half_as_ushort(__float2half(1.0f - p));
    }

    block_reduce_atomic(local, ws + 1, sdata);
}

// 16 edges (32 gathers) per thread, exact cover. The 32 gathers are issued
// as volatile inline-asm global_load_ushort with distinct "=v" outputs:
// volatile asms keep program order among themselves and force 32 live dest
// VGPRs, so the compiler cannot split the batch into issue/wait/consume
// chunks. The asm loads are invisible to the compiler's vmcnt bookkeeping,
// so the explicit s_waitcnt + sched_barrier pair before consumption is a
// CORRECTNESS requirement (no HW scoreboard on VMEM dests).
__global__ void edge_sum_kernel(
        const unsigned short* __restrict__ qt,
        const int* __restrict__ row,
        const int* __restrict__ col,
        double* __restrict__ ws,
        long long n_edges,
        int sentinel) {
    __shared__ double sdata[THREADS / 64];
    long long n4 = n_edges >> 2;   // int4 groups
    long long G4 = n4 >> 2;        // 4 groups per thread
    long long t  = (long long)blockIdx.x * blockDim.x + threadIdx.x;

    const int4v* row4 = (const int4v*)row;
    const int4v* col4 = (const int4v*)col;

    float local = 0.0f;
    if (t < G4) {
        // ---- index loads (8x dwordx4, nontemporal: streamed once) ----
        int4v u[4], v[4];
        #pragma unroll
        for (int k = 0; k < 4; ++k) {
            u[k] = __builtin_nontemporal_load(&row4[t + (long long)k * G4]);
            v[k] = __builtin_nontemporal_load(&col4[t + (long long)k * G4]);
        }

        int iu[16], iv[16];
        #pragma unroll
        for (int k = 0; k < 4; ++k) {
            iu[4 * k + 0] = u[k].x;
            iu[4 * k + 1] = u[k].y;
            iu[4 * k + 2] = u[k].z;
            iu[4 * k + 3] = u[k].w;
            iv[4 * k + 0] = (u[k].x == v[k].x) ? sentinel : v[k].x;
            iv[4 * k + 1] = (u[k].y == v[k].y) ? sentinel : v[k].y;
            iv[4 * k + 2] = (u[k].z == v[k].z) ? sentinel : v[k].z;
            iv[4 * k + 3] = (u[k].w == v[k].w) ? sentinel : v[k].w;
        }

        unsigned long long base = (unsigned long long)qt;
        unsigned av[16], bv[16];

        // ---- issue all 32 gathers, no intervening waits ----
        #pragma unroll
        for (int i = 0; i < 16; ++i) {
            unsigned long long ua = base + 2ull * (unsigned)iu[i];
            asm volatile("global_load_ushort %0, %1, off"
                         : "=v"(av[i]) : "v"(ua));
        }
        #pragma unroll
        for (int i = 0; i < 16; ++i) {
            unsigned long long va = base + 2ull * (unsigned)iv[i];
            asm volatile("global_load_ushort %0, %1, off"
                         : "=v"(bv[i]) : "v"(va));
        }

        // ---- single drain, fenced against consumer hoisting (rule #18) ----
        asm volatile("s_waitcnt vmcnt(0)" ::: "memory");
        __builtin_amdgcn_sched_barrier(0);

        // ---- consume ----
        #pragma unroll
        for (int i = 0; i < 16; ++i)
            local += h2f_bits(av[i]) * h2f_bits(bv[i]);
    }

    // tail: edges past 16*G4 (empty when n_edges % 16 == 0)
    long long covered = G4 << 4;
    long long total_threads = (long long)gridDim.x * blockDim.x;
    for (long long e = covered + t; e < n_edges; e += total_threads) {
        int uu = row[e], vv = col[e];
        int vr = (uu == vv) ? sentinel : vv;
        local += h2f_bits(qt[uu]) * h2f_bits(qt[vr]);
    }

    block_reduce_atomic(local, ws, sdata);
}

__global__ void finalize_kernel(const double* __restrict__ ws,
                                const int* __restrict__ batch,
                                long long n_nodes,
                                const float* __restrict__ pc,
                                float* __restrict__ out) {
    double edge_s = ws[0];
    double prob_s = ws[1];
    double G = (double)(batch[n_nodes - 1] + 1);  // batch is sorted
    double ed = edge_s / G;
    double ew = prob_s / G;
    double loss = (double)pc[0] * ed + ew;
    out[0] = (float)loss;
    out[1] = (float)ew;
    out[2] = (float)ed;
}

extern "C" void kernel_launch(void* const* d_in, const int* in_sizes, int n_in,
                              void* d_out, int out_size, void* d_ws, size_t ws_size,
                              hipStream_t stream) {
    const float* probs = (const float*)d_in[0];
    const int* edge_index = (const int*)d_in[1];   // harness passes integers as int32
    const int* batch = (const int*)d_in[2];
    const float* pc = (const float*)d_in[3];

    long long n_nodes = (long long)in_sizes[0];
    long long n_edges = (long long)in_sizes[1] / 2;
    const int* row = edge_index;
    const int* col = edge_index + n_edges;

    double* ws = (double*)d_ws;
    hipMemsetAsync(ws, 0, 2 * sizeof(double), stream);

    unsigned short* qt = (unsigned short*)((char*)d_ws + 256);
    build_table_kernel<<<512, THREADS, 0, stream>>>(probs, qt, ws, n_nodes);

    long long T = (n_edges >> 2) >> 2;           // 16 edges per thread
    long long blocks = (T + THREADS - 1) / THREADS;
    if (blocks < 1) blocks = 1;
    edge_sum_kernel<<<(int)blocks, THREADS, 0, stream>>>(qt, row, col, ws,
                                                         n_edges, (int)n_nodes);

    finalize_kernel<<<1, 1, 0, stream>>>(ws, batch, n_nodes, pc, (float*)d_out);
}